// Round 10
// baseline (428.002 us; speedup 1.0000x reference)
//
#include <hip/hip_runtime.h>
#include <hip/hip_bf16.h>

#define N 8192
#define FIN 128
#define FOUT 64
#define ALPHA 0.2f
#define LOG2E 1.44269504f
#define JSPLIT 4
#define JSPAN (N / JSPLIT)    // 2048 j per block; 512 j per wave = 16 units of 32

typedef __attribute__((ext_vector_type(8))) short short8;
typedef __attribute__((ext_vector_type(4))) float f32x4;

static __device__ __forceinline__ unsigned fkey(float x) {
    unsigned u = __float_as_uint(x);
    return (u >> 31) ? ~u : (u | 0x80000000u);
}
static __device__ __forceinline__ float fdecode(unsigned k) {
    unsigned u = (k & 0x80000000u) ? (k & 0x7FFFFFFFu) : ~k;
    return __uint_as_float(u);
}

// ---------------- k_prep: Wh = h@W; s2 = (Wh@a1)*log2e; t2 = (Wh@a2)*log2e --------
__global__ __launch_bounds__(256) void k_prep(const float* __restrict__ h,
                                              const float* __restrict__ W,
                                              const float* __restrict__ a,
                                              float* __restrict__ Wh,
                                              float* __restrict__ s2,
                                              float* __restrict__ t2,
                                              unsigned* __restrict__ keys) {
    __shared__ float lH[16 * FIN];
    __shared__ float lW[FIN * FOUT];
    __shared__ float red[8];
    const int tid = threadIdx.x;
    const int r0 = blockIdx.x * 16;
    {
        const float4* src = (const float4*)(h + (size_t)r0 * FIN);
        float4* dst = (float4*)lH;
        for (int i = tid; i < 16 * FIN / 4; i += 256) dst[i] = src[i];
        const float4* ws_ = (const float4*)W;
        float4* dw = (float4*)lW;
        for (int i = tid; i < FIN * FOUT / 4; i += 256) dw[i] = ws_[i];
    }
    __syncthreads();
    const int wave = tid >> 6, lane = tid & 63;
    float acc[4] = {0.f, 0.f, 0.f, 0.f};
    for (int k = 0; k < FIN; ++k) {
        float wv = lW[k * FOUT + lane];
#pragma unroll
        for (int r = 0; r < 4; ++r)
            acc[r] = fmaf(lH[(wave * 4 + r) * FIN + k], wv, acc[r]);
    }
    const float a1 = a[lane], a2 = a[FOUT + lane];
    float smx = -1e30f, tmx = -1e30f;
#pragma unroll
    for (int r = 0; r < 4; ++r) {
        int row = r0 + wave * 4 + r;
        Wh[(size_t)row * FOUT + lane] = acc[r];
        float sv = acc[r] * a1, tv = acc[r] * a2;
#pragma unroll
        for (int off = 32; off; off >>= 1) {
            sv += __shfl_xor(sv, off);
            tv += __shfl_xor(tv, off);
        }
        sv *= LOG2E; tv *= LOG2E;      // pre-scale: exp(x) -> exp2(x')
        if (lane == 0) { s2[row] = sv; t2[row] = tv; }
        smx = fmaxf(smx, sv);
        tmx = fmaxf(tmx, tv);
    }
    if (lane == 0) { red[wave] = smx; red[4 + wave] = tmx; }
    __syncthreads();
    if (tid == 0) {
        float ms = fmaxf(fmaxf(red[0], red[1]), fmaxf(red[2], red[3]));
        float mt = fmaxf(fmaxf(red[4], red[5]), fmaxf(red[6], red[7]));
        atomicMax(keys + 0, fkey(ms));
        atomicMax(keys + 1, fkey(mt));
    }
}

// ---------------- k_pack: Wh fp32 -> bf16 B-fragment layout ------------------------
// B-frag (16x16x32): lane holds col n = lane&15, k = (lane>>4)*8 + e
__global__ __launch_bounds__(256) void k_pack(const float* __restrict__ Wh,
                                              __hip_bfloat16* __restrict__ WhB) {
    const int c = blockIdx.x;
    const int tn = threadIdx.x >> 6;
    const int lane = threadIdx.x & 63;
    const int quad = lane >> 4, l16 = lane & 15;
    const float* src = Wh + ((size_t)(c * 32 + quad * 8)) * FOUT + tn * 16 + l16;
    union { unsigned short u[8]; short8 v; } frag;
#pragma unroll
    for (int e = 0; e < 8; ++e) {
        __hip_bfloat16 b = __float2bfloat16(src[(size_t)e * FOUT]);
        frag.u[e] = *(unsigned short*)&b;
    }
    *(short8*)&WhB[(((size_t)c * 4 + tn) * 64 + lane) * 8] = frag.v;
}

// ---------------- k_attn: fused mask+softmax+PV, all-register pipeline -------------
// Grid (N/16, 4); block 256 = 4 waves. Wave w owns 16 rows x units [16w..16w+16)
// of its j-quarter: fully independent (no LDS, no barriers in the K-loop).
// Depth-2 rotating register slots for adj/t/B: loaded at body bottom, consumed
// one full body later; compiler emits precise vmcnt(N), in-order queue never
// force-drains newer prefetches. lsum via 5th MFMA against all-ones B-frag.
__global__ __launch_bounds__(256) void k_attn(const float* __restrict__ adj,
                                              const __hip_bfloat16* __restrict__ WhB,
                                              const float* __restrict__ s2,
                                              const float* __restrict__ t2,
                                              const unsigned* __restrict__ keys,
                                              float* __restrict__ acc_ws,
                                              float* __restrict__ l_ws) {
    __shared__ float ep[4][4][64][4];  // 16 KB epilogue only
    const int wave = threadIdx.x >> 6, lane = threadIdx.x & 63;
    const int quad = lane >> 4, l16 = lane & 15;
    const int i0 = blockIdx.x * 16;
    const int jw = blockIdx.y * JSPAN + wave * 512;   // wave's 512-j span

    const float* ga = adj + (size_t)(i0 + l16) * N + jw + quad * 8;
    const float* gt = t2 + jw + quad * 8;
    const int cb = jw >> 5;                            // B chunk base
    const short8* BF = (const short8*)WhB;

    const float mraw = fdecode(keys[0]) + fdecode(keys[1]);
    const float mm = mraw > 0.f ? mraw : ALPHA * mraw;
    const float sm = s2[i0 + l16];

    const short8 onesv = {0x3F80, 0x3F80, 0x3F80, 0x3F80, 0x3F80, 0x3F80, 0x3F80, 0x3F80};

    f32x4 acc0 = {0,0,0,0}, acc1 = {0,0,0,0}, acc2 = {0,0,0,0}, acc3 = {0,0,0,0};
    f32x4 accL = {0,0,0,0};

    float4 Aa[2], Ab[2], Ta[2], Tb[2];
    short8 B0[2], B1[2], B2[2], B3[2];

#define LOADU(s, u)                                                              \
    do {                                                                         \
        Aa[s] = *(const float4*)(ga + (u) * 32);                                 \
        Ab[s] = *(const float4*)(ga + (u) * 32 + 4);                             \
        Ta[s] = *(const float4*)(gt + (u) * 32);                                 \
        Tb[s] = *(const float4*)(gt + (u) * 32 + 4);                             \
        const size_t c_ = (size_t)(cb + (u)) * 4;                                \
        B0[s] = BF[(c_ + 0) * 64 + lane];                                        \
        B1[s] = BF[(c_ + 1) * 64 + lane];                                        \
        B2[s] = BF[(c_ + 2) * 64 + lane];                                        \
        B3[s] = BF[(c_ + 3) * 64 + lane];                                        \
    } while (0)

#define PROCU(s)                                                                 \
    do {                                                                         \
        union { __hip_bfloat162 h2[4]; short8 v; } af;                           \
        _Pragma("unroll")                                                        \
        for (int pp = 0; pp < 4; ++pp) {                                         \
            float a0 = (pp < 2) ? ((const float*)&Aa[s])[2 * pp]                 \
                                : ((const float*)&Ab[s])[2 * pp - 4];            \
            float a1 = (pp < 2) ? ((const float*)&Aa[s])[2 * pp + 1]             \
                                : ((const float*)&Ab[s])[2 * pp - 3];            \
            float t0 = (pp < 2) ? ((const float*)&Ta[s])[2 * pp]                 \
                                : ((const float*)&Tb[s])[2 * pp - 4];            \
            float t1 = (pp < 2) ? ((const float*)&Ta[s])[2 * pp + 1]             \
                                : ((const float*)&Tb[s])[2 * pp - 3];            \
            float x0 = sm + t0, x1 = sm + t1;                                    \
            float le0 = fmaxf(x0, ALPHA * x0), le1 = fmaxf(x1, ALPHA * x1);      \
            float p0 = a0 * exp2f(le0 - mm), p1 = a1 * exp2f(le1 - mm);          \
            af.h2[pp] = __float22bfloat162_rn(make_float2(p0, p1));              \
        }                                                                        \
        acc0 = __builtin_amdgcn_mfma_f32_16x16x32_bf16(af.v, B0[s], acc0, 0, 0, 0); \
        acc1 = __builtin_amdgcn_mfma_f32_16x16x32_bf16(af.v, B1[s], acc1, 0, 0, 0); \
        acc2 = __builtin_amdgcn_mfma_f32_16x16x32_bf16(af.v, B2[s], acc2, 0, 0, 0); \
        acc3 = __builtin_amdgcn_mfma_f32_16x16x32_bf16(af.v, B3[s], acc3, 0, 0, 0); \
        accL = __builtin_amdgcn_mfma_f32_16x16x32_bf16(af.v, onesv, accL, 0, 0, 0); \
    } while (0)

    // prologue: units 0,1 into slots 0,1
    LOADU(0, 0);
    LOADU(1, 1);
    // body k: consume units 2k,2k+1; refill slots with units 2k+2,2k+3 at bottom.
    // unroll 1 keeps the rotation loop-carried: refills cannot sink past the
    // backedge, consumes cannot hoist above it -> guaranteed 1-body slack.
#pragma unroll 1
    for (int k = 0; k < 8; ++k) {
        PROCU(0);
        PROCU(1);
        const int u0 = (2 * k + 2 > 14) ? 14 : 2 * k + 2;  // clamp: tail reloads
        const int u1 = (2 * k + 3 > 15) ? 15 : 2 * k + 3;  // L2-hot, never consumed
        LOADU(0, u0);
        LOADU(1, u1);
    }
#undef LOADU
#undef PROCU

    // lsum: accL cols all equal; row = quad*4 + reg. One lane per row publishes.
    if (l16 == 0) {
#pragma unroll
        for (int r = 0; r < 4; ++r)
            atomicAdd(&l_ws[i0 + quad * 4 + r], accL[r]);
    }

    // epilogue: cross-wave reduce (waves cover disjoint j), then atomicAdd.
    *(f32x4*)&ep[wave][0][lane][0] = acc0;
    *(f32x4*)&ep[wave][1][lane][0] = acc1;
    *(f32x4*)&ep[wave][2][lane][0] = acc2;
    *(f32x4*)&ep[wave][3][lane][0] = acc3;
    __syncthreads();
    const int tile = wave;
    f32x4 tot = {0, 0, 0, 0};
#pragma unroll
    for (int w = 0; w < 4; ++w) {
        f32x4 c = *(const f32x4*)&ep[w][tile][lane][0];
        tot[0] += c[0]; tot[1] += c[1]; tot[2] += c[2]; tot[3] += c[3];
    }
#pragma unroll
    for (int r = 0; r < 4; ++r) {
        int row = quad * 4 + r;  // C/D: row=(lane>>4)*4+reg, col=l16 within tile
        atomicAdd(&acc_ws[(size_t)(i0 + row) * FOUT + tile * 16 + l16], tot[r]);
    }
}

// ---------------- k_final: out = elu(acc/l) ---------------------------------------
__global__ __launch_bounds__(256) void k_final(const float* __restrict__ acc_ws,
                                               const float* __restrict__ l_ws,
                                               float* __restrict__ out) {
    const int idx = blockIdx.x * 256 + threadIdx.x;   // one float4 per thread
    const int row = idx >> 4;                          // 16 float4 per row
    const float inv = 1.0f / l_ws[row];
    float4 a = ((const float4*)acc_ws)[idx];
    float4 o;
#pragma unroll
    for (int r = 0; r < 4; ++r) {
        float v = ((const float*)&a)[r] * inv;
        ((float*)&o)[r] = v > 0.f ? v : (exp2f(v * LOG2E) - 1.f);
    }
    ((float4*)out)[idx] = o;
}

extern "C" void kernel_launch(void* const* d_in, const int* in_sizes, int n_in,
                              void* d_out, int out_size, void* d_ws, size_t ws_size,
                              hipStream_t stream) {
    const float* h   = (const float*)d_in[0];
    const float* adj = (const float*)d_in[1];
    const float* W   = (const float*)d_in[2];
    const float* a   = (const float*)d_in[3];
    float* out = (float*)d_out;

    char* base = (char*)d_ws;
    float* Wh = (float*)base;                        base += (size_t)N * FOUT * 4;
    __hip_bfloat16* WhB = (__hip_bfloat16*)base;     base += (size_t)N * FOUT * 2;
    float* s2 = (float*)base;                        base += (size_t)N * 4;
    float* t2 = (float*)base;                        base += (size_t)N * 4 + 1024;
    float* acc_ws = (float*)base;                    base += (size_t)N * FOUT * 4;
    float* l_ws = (float*)base;                      base += (size_t)N * 4;
    unsigned* keys = (unsigned*)base;

    hipMemsetAsync(acc_ws, 0, ((size_t)N * FOUT + N) * 4 + 2 * sizeof(unsigned), stream);
    k_prep<<<N / 16, 256, 0, stream>>>(h, W, a, Wh, s2, t2, keys);
    k_pack<<<N / 32, 256, 0, stream>>>(Wh, WhB);
    dim3 ag(N / 16, JSPLIT);
    k_attn<<<ag, 256, 0, stream>>>(adj, WhB, s2, t2, keys, acc_ws, l_ws);
    k_final<<<N * FOUT / 4 / 256, 256, 0, stream>>>(acc_ws, l_ws, out);
}